// Round 5
// baseline (343.181 us; speedup 1.0000x reference)
//
#include <hip/hip_runtime.h>
#include <hip/hip_bf16.h>

#define NNODES 50000
#define NEDGES 800000
#define ETOT   850000
#define NEG_SLOPE 0.2f
#define LN_EPS 1e-5f
#define SM_EPS 1e-16f
#define NBUCK 196                 // ceil(50000/256) buckets of 256 nodes
#define NBLK 208                  // ceil(850000/4096) edge chunks
#define CHUNK 4096

typedef short bf16x8 __attribute__((ext_vector_type(8)));
typedef float f32x4  __attribute__((ext_vector_type(4)));
typedef float v2f    __attribute__((ext_vector_type(2)));

__device__ __forceinline__ unsigned pack_bf2(float a, float b) {
    __hip_bfloat162 p;
    p.x = __float2bfloat16(a);
    p.y = __float2bfloat16(b);
    return *reinterpret_cast<unsigned*>(&p);
}

__device__ __forceinline__ v2f bf2_to_f2(unsigned u) {
    v2f r;
    r.x = __int_as_float((int)(u << 16));
    r.y = __int_as_float((int)(u & 0xFFFF0000u));
    return r;
}

template <int CTRL>
__device__ __forceinline__ float dpp_add(float x) {
    return x + __int_as_float(__builtin_amdgcn_update_dpp(
        0, __float_as_int(x), CTRL, 0xF, 0xF, true));
}
// sum over aligned 8-lane group, result in all 8 lanes
// xor1, xor2, then row_half_mirror (0x141: l <-> 7-l within each 8)
__device__ __forceinline__ float red8(float x) {
    x = dpp_add<0xB1>(x);
    x = dpp_add<0x4E>(x);
    x = dpp_add<0x141>(x);
    return x;
}

// per-lane partial of att-dot over 8 features (4 v2f lanes-slices)
__device__ __forceinline__ float edot4(v2f x0, v2f x1, v2f x2, v2f x3,
                                       v2f r0, v2f r1, v2f r2, v2f r3,
                                       v2f a0, v2f a1, v2f a2, v2f a3) {
    v2f s0 = x0 + r0, s1 = x1 + r1, s2 = x2 + r2, s3 = x3 + r3;
    v2f t0 = __builtin_elementwise_max(s0, s0 * NEG_SLOPE);
    v2f t1 = __builtin_elementwise_max(s1, s1 * NEG_SLOPE);
    v2f t2 = __builtin_elementwise_max(s2, s2 * NEG_SLOPE);
    v2f t3 = __builtin_elementwise_max(s3, s3 * NEG_SLOPE);
    v2f d = t0 * a0 + t1 * a1 + t2 * a2 + t3 * a3;
    return d.x + d.y;
}

// XOR-swizzled LDS offset for 64-col short tiles (16B granules)
__device__ __forceinline__ int sw(int row, int c8) {
    return (row << 6) + ((c8 ^ (row & 7)) << 3);
}

// ---------------- weights cast + csr pad + sentinel (tiny) ----------------
__global__ void k_cast_w(const float* __restrict__ W1l, const float* __restrict__ W1r,
                         const float* __restrict__ W2l, const float* __restrict__ W2r,
                         __hip_bfloat16* __restrict__ w1lT, __hip_bfloat16* __restrict__ w1rT,
                         __hip_bfloat16* __restrict__ w2lT, __hip_bfloat16* __restrict__ w2rT,
                         unsigned short* __restrict__ csr_src, int* __restrict__ rowstart) {
    int t = blockIdx.x * 256 + threadIdx.x;
    if (t < 16) csr_src[ETOT + t] = 0;       // pad: node-0 reads, weight-masked
    if (t == 16) rowstart[NNODES] = ETOT;    // sentinel
    if (t < 65536) {
        int k = t >> 8, n = t & 255;
        w1lT[n * 256 + k] = __float2bfloat16(W1l[t]);
    } else if (t < 131072) {
        int u = t - 65536; int k = u >> 8, n = u & 255;
        w1rT[n * 256 + k] = __float2bfloat16(W1r[u]);
    } else if (t < 135168) {
        int u = t - 131072; int k = u >> 6, n = u & 63;
        w2lT[n * 64 + k] = __float2bfloat16(W2l[u]);
    } else if (t < 139264) {
        int u = t - 135168; int k = u >> 6, n = u & 63;
        w2rT[n * 64 + k] = __float2bfloat16(W2r[u]);
    }
}

// ---------------- bucket histogram: LDS only, per-(bucket,block) counts ----------
__global__ void __launch_bounds__(256) k_bhist(const int* __restrict__ ei,
                                               int* __restrict__ part) {
    __shared__ int h[256];
    h[threadIdx.x] = 0;
    __syncthreads();
    const int base = blockIdx.x * CHUNK;
    #pragma unroll
    for (int it = 0; it < 16; ++it) {
        int e = base + it * 256 + threadIdx.x;
        if (e < ETOT) {
            int dst = (e < NEDGES) ? ei[NEDGES + e] : (e - NEDGES);
            atomicAdd(&h[dst >> 8], 1);
        }
    }
    __syncthreads();
    part[threadIdx.x * NBLK + blockIdx.x] = h[threadIdx.x];   // bucket-major
}

// ---------------- generic block-level exclusive scan ----------------
__global__ void k_scan_blk(const int* __restrict__ in, int n,
                           int* __restrict__ out, int* __restrict__ bsum) {
    __shared__ int s[256];
    int t = threadIdx.x;
    int i = blockIdx.x * 256 + t;
    int v = (i < n) ? in[i] : 0;
    s[t] = v;
    __syncthreads();
    #pragma unroll
    for (int off = 1; off < 256; off <<= 1) {
        int add = (t >= off) ? s[t - off] : 0;
        __syncthreads();
        s[t] += add;
        __syncthreads();
    }
    if (i < n) out[i] = s[t] - v;
    if (t == 255) bsum[blockIdx.x] = s[255];
}

__global__ void k_scan_top(int* __restrict__ bs, int nb) {   // nb <= 256
    __shared__ int s[256];
    int t = threadIdx.x;
    int v = (t < nb) ? bs[t] : 0;
    s[t] = v;
    __syncthreads();
    #pragma unroll
    for (int off = 1; off < 256; off <<= 1) {
        int add = (t >= off) ? s[t - off] : 0;
        __syncthreads();
        s[t] += add;
        __syncthreads();
    }
    if (t < nb) bs[t] = s[t] - v;
}

__global__ void k_scan_add(int* __restrict__ out, const int* __restrict__ bs, int n) {
    int i = blockIdx.x * 256 + threadIdx.x;
    if (i < n) out[i] += bs[i >> 8];
}

// ---------------- bucket scatter: LDS cursors, coalesced-run pair writes --------
__global__ void __launch_bounds__(256) k_bscatter(const int* __restrict__ ei,
                                                  const int* __restrict__ partoff,
                                                  unsigned* __restrict__ pairs) {
    __shared__ int cnt[256];
    const int t = threadIdx.x;
    cnt[t] = partoff[t * NBLK + blockIdx.x];
    __syncthreads();
    const int base = blockIdx.x * CHUNK;
    #pragma unroll
    for (int it = 0; it < 16; ++it) {
        int e = base + it * 256 + t;
        if (e < ETOT) {
            int dst, src;
            if (e < NEDGES) { dst = ei[NEDGES + e]; src = ei[e]; }
            else            { dst = e - NEDGES;     src = dst; }
            int pos = atomicAdd(&cnt[dst >> 8], 1);
            pairs[pos] = ((unsigned)dst << 16) | (unsigned)src;
        }
    }
}

// ---------------- fused per-bucket: count + LDS scan + rowstart + scatter -------
__global__ void __launch_bounds__(256) k_nfinal(const unsigned* __restrict__ pairs,
                                                const int* __restrict__ partoff,
                                                int* __restrict__ rowstart,
                                                unsigned short* __restrict__ csr_src) {
    __shared__ int h[256];
    __shared__ int cur[256];
    const int b = blockIdx.x;
    const int t = threadIdx.x;
    const int r0 = partoff[b * NBLK];
    const int r1 = partoff[(b + 1) * NBLK];
    h[t] = 0;
    __syncthreads();
    for (int i = r0 + t; i < r1; i += 1024) {
        unsigned p0 = pairs[i];
        bool v1 = (i + 256 < r1), v2 = (i + 512 < r1), v3 = (i + 768 < r1);
        unsigned p1 = v1 ? pairs[i + 256] : 0u;
        unsigned p2 = v2 ? pairs[i + 512] : 0u;
        unsigned p3 = v3 ? pairs[i + 768] : 0u;
        atomicAdd(&h[(p0 >> 16) & 255], 1);
        if (v1) atomicAdd(&h[(p1 >> 16) & 255], 1);
        if (v2) atomicAdd(&h[(p2 >> 16) & 255], 1);
        if (v3) atomicAdd(&h[(p3 >> 16) & 255], 1);
    }
    __syncthreads();
    int v = h[t];
    cur[t] = v;
    __syncthreads();
    #pragma unroll
    for (int off = 1; off < 256; off <<= 1) {
        int add = (t >= off) ? cur[t - off] : 0;
        __syncthreads();
        cur[t] += add;
        __syncthreads();
    }
    int start = r0 + cur[t] - v;
    int node = (b << 8) + t;
    if (node < NNODES) rowstart[node] = start;
    cur[t] = start;
    __syncthreads();
    for (int i = r0 + t; i < r1; i += 1024) {
        unsigned p0 = pairs[i];
        bool v1 = (i + 256 < r1), v2 = (i + 512 < r1), v3 = (i + 768 < r1);
        unsigned p1 = v1 ? pairs[i + 256] : 0u;
        unsigned p2 = v2 ? pairs[i + 512] : 0u;
        unsigned p3 = v3 ? pairs[i + 768] : 0u;
        int q0 = atomicAdd(&cur[(p0 >> 16) & 255], 1);
        csr_src[q0] = (unsigned short)(p0 & 0xFFFFu);
        if (v1) { int q = atomicAdd(&cur[(p1 >> 16) & 255], 1); csr_src[q] = (unsigned short)(p1 & 0xFFFFu); }
        if (v2) { int q = atomicAdd(&cur[(p2 >> 16) & 255], 1); csr_src[q] = (unsigned short)(p2 & 0xFFFFu); }
        if (v3) { int q = atomicAdd(&cur[(p3 >> 16) & 255], 1); csr_src[q] = (unsigned short)(p3 & 0xFFFFu); }
    }
}

// ---------------- layer-1 GEMM: f32 A cast in-stage, full N=256, dual output ----
// Single pass over A (x read once); all 4 B n-slices LDS-resident (72 KB).
__global__ __launch_bounds__(256) void k_gemm_x1(
    const float* __restrict__ X,
    const __hip_bfloat16* __restrict__ WTl,
    const __hip_bfloat16* __restrict__ WTr,
    __hip_bfloat16* __restrict__ Cl,
    __hip_bfloat16* __restrict__ Cr, int M)
{
    __shared__ short As[64 * 64];
    __shared__ short Bls[4][64 * 64];
    __shared__ short Brs[4][64 * 64];
    const int t = threadIdx.x;
    const int m0 = blockIdx.x * 64;
    const int wave = t >> 6, lane = t & 63;
    const int wm = wave & 1, wn = wave >> 1;
    const int l15 = lane & 15, quad = lane >> 4;

    f32x4 accl[4][2][2] = {};
    f32x4 accr[4][2][2] = {};
    for (int k0 = 0; k0 < 256; k0 += 64) {
        __syncthreads();
        #pragma unroll
        for (int it = 0; it < 2; ++it) {
            int f = t + 256 * it;
            int r = f >> 3, c8 = f & 7;
            int row = m0 + r;
            uint4 v = make_uint4(0u, 0u, 0u, 0u);
            if (row < M) {
                const float4* src = reinterpret_cast<const float4*>(
                    X + (size_t)row * 256 + k0 + c8 * 8);
                float4 a = src[0], b = src[1];
                v.x = pack_bf2(a.x, a.y);
                v.y = pack_bf2(a.z, a.w);
                v.z = pack_bf2(b.x, b.y);
                v.w = pack_bf2(b.z, b.w);
            }
            *reinterpret_cast<uint4*>(&As[sw(r, c8)]) = v;
        }
        #pragma unroll
        for (int it = 0; it < 8; ++it) {
            int f = t + 256 * it;                 // 0..2047
            int s = f >> 9, ws = f & 511;
            int n = ws >> 3, c8 = ws & 7;
            int ng = s * 64 + n;
            *reinterpret_cast<uint4*>(&Bls[s][sw(n, c8)]) =
                *reinterpret_cast<const uint4*>(&WTl[(size_t)ng * 256 + k0 + c8 * 8]);
            *reinterpret_cast<uint4*>(&Brs[s][sw(n, c8)]) =
                *reinterpret_cast<const uint4*>(&WTr[(size_t)ng * 256 + k0 + c8 * 8]);
        }
        __syncthreads();
        #pragma unroll
        for (int kk8 = 0; kk8 < 8; kk8 += 4) {
            bf16x8 af[2];
            #pragma unroll
            for (int mi = 0; mi < 2; ++mi)
                af[mi] = *reinterpret_cast<const bf16x8*>(
                    &As[sw(wm * 32 + mi * 16 + l15, kk8 + quad)]);
            #pragma unroll
            for (int s = 0; s < 4; ++s) {
                bf16x8 bl[2], br[2];
                #pragma unroll
                for (int ni = 0; ni < 2; ++ni) {
                    int rB = wn * 32 + ni * 16 + l15;
                    bl[ni] = *reinterpret_cast<const bf16x8*>(&Bls[s][sw(rB, kk8 + quad)]);
                    br[ni] = *reinterpret_cast<const bf16x8*>(&Brs[s][sw(rB, kk8 + quad)]);
                }
                #pragma unroll
                for (int mi = 0; mi < 2; ++mi)
                    #pragma unroll
                    for (int ni = 0; ni < 2; ++ni) {
                        accl[s][mi][ni] = __builtin_amdgcn_mfma_f32_16x16x32_bf16(
                            af[mi], bl[ni], accl[s][mi][ni], 0, 0, 0);
                        accr[s][mi][ni] = __builtin_amdgcn_mfma_f32_16x16x32_bf16(
                            af[mi], br[ni], accr[s][mi][ni], 0, 0, 0);
                    }
            }
        }
    }
    #pragma unroll
    for (int s = 0; s < 4; ++s)
        #pragma unroll
        for (int mi = 0; mi < 2; ++mi)
            #pragma unroll
            for (int ni = 0; ni < 2; ++ni)
                #pragma unroll
                for (int r = 0; r < 4; ++r) {
                    int row = m0 + wm * 32 + mi * 16 + quad * 4 + r;
                    int col = s * 64 + wn * 32 + ni * 16 + l15;
                    if (row < M) {
                        Cl[(size_t)row * 256 + col] = __float2bfloat16(accl[s][mi][ni][r]);
                        Cr[(size_t)row * 256 + col] = __float2bfloat16(accr[s][mi][ni][r]);
                    }
                }
}

// ---------------- layer-2 GEMM (bf16 A, N=64) -----------------------------------
__global__ __launch_bounds__(256) void k_gemm_dual(
    const __hip_bfloat16* __restrict__ A,
    const __hip_bfloat16* __restrict__ WTl,
    const __hip_bfloat16* __restrict__ WTr,
    __hip_bfloat16* __restrict__ Cl,
    __hip_bfloat16* __restrict__ Cr, int M)
{
    __shared__ short As[64 * 64];
    __shared__ short Bls[64 * 64];
    __shared__ short Brs[64 * 64];
    const int t = threadIdx.x;
    const int m0 = blockIdx.x * 64;
    const int wave = t >> 6, lane = t & 63;
    const int wm = wave & 1, wn = wave >> 1;
    const int l15 = lane & 15, quad = lane >> 4;

    f32x4 accl[2][2] = {};
    f32x4 accr[2][2] = {};
    {
        #pragma unroll
        for (int it = 0; it < 2; ++it) {
            int f = t + 256 * it;
            int r = f >> 3, c8 = f & 7;
            int row = m0 + r;
            uint4 v = make_uint4(0u, 0u, 0u, 0u);
            if (row < M) v = *reinterpret_cast<const uint4*>(&A[(size_t)row * 64 + c8 * 8]);
            *reinterpret_cast<uint4*>(&As[sw(r, c8)]) = v;
        }
        #pragma unroll
        for (int it = 0; it < 2; ++it) {
            int f = t + 256 * it;
            int n = f >> 3, c8 = f & 7;
            *reinterpret_cast<uint4*>(&Bls[sw(n, c8)]) =
                *reinterpret_cast<const uint4*>(&WTl[(size_t)n * 64 + c8 * 8]);
            *reinterpret_cast<uint4*>(&Brs[sw(n, c8)]) =
                *reinterpret_cast<const uint4*>(&WTr[(size_t)n * 64 + c8 * 8]);
        }
        __syncthreads();
        #pragma unroll
        for (int kk8 = 0; kk8 < 8; kk8 += 4) {
            bf16x8 af[2], bl[2], br[2];
            #pragma unroll
            for (int mi = 0; mi < 2; ++mi)
                af[mi] = *reinterpret_cast<const bf16x8*>(
                    &As[sw(wm * 32 + mi * 16 + l15, kk8 + quad)]);
            #pragma unroll
            for (int ni = 0; ni < 2; ++ni) {
                int rB = wn * 32 + ni * 16 + l15;
                bl[ni] = *reinterpret_cast<const bf16x8*>(&Bls[sw(rB, kk8 + quad)]);
                br[ni] = *reinterpret_cast<const bf16x8*>(&Brs[sw(rB, kk8 + quad)]);
            }
            #pragma unroll
            for (int mi = 0; mi < 2; ++mi)
                #pragma unroll
                for (int ni = 0; ni < 2; ++ni) {
                    accl[mi][ni] = __builtin_amdgcn_mfma_f32_16x16x32_bf16(
                        af[mi], bl[ni], accl[mi][ni], 0, 0, 0);
                    accr[mi][ni] = __builtin_amdgcn_mfma_f32_16x16x32_bf16(
                        af[mi], br[ni], accr[mi][ni], 0, 0, 0);
                }
        }
    }
    #pragma unroll
    for (int mi = 0; mi < 2; ++mi)
        #pragma unroll
        for (int ni = 0; ni < 2; ++ni)
            #pragma unroll
            for (int r = 0; r < 4; ++r) {
                int row = m0 + wm * 32 + mi * 16 + quad * 4 + r;
                int col = wn * 32 + ni * 16 + l15;
                if (row < M) {
                    Cl[(size_t)row * 64 + col] = __float2bfloat16(accl[mi][ni][r]);
                    Cr[(size_t)row * 64 + col] = __float2bfloat16(accr[mi][ni][r]);
                }
            }
}

// ---------------- layer 1: one node per wave; 16B gathers, 8 edges in flight ----
// lane = [half:1][head:2][slice:3]; 32 lanes cover a 512B row (8 feats/lane).
__global__ void __launch_bounds__(64) k_node1(
                        const __hip_bfloat16* __restrict__ xl,
                        const __hip_bfloat16* __restrict__ xr,
                        const int* __restrict__ rowstart,
                        const unsigned short* __restrict__ csr_src,
                        const float* __restrict__ att,   // [4,64]
                        const float* __restrict__ bias,  // [64]
                        const float* __restrict__ lng,
                        const float* __restrict__ lnb,
                        __hip_bfloat16* __restrict__ h1b) {
    const int i = blockIdx.x;
    const int lane = threadIdx.x;
    const int half = lane >> 5;
    const int fs = (lane & 31) * 8;      // feature slice

    uint4 rr = *reinterpret_cast<const uint4*>(xr + (size_t)i * 256 + fs);
    v2f r0 = bf2_to_f2(rr.x), r1 = bf2_to_f2(rr.y),
        r2 = bf2_to_f2(rr.z), r3 = bf2_to_f2(rr.w);
    const float4 aa = *reinterpret_cast<const float4*>(att + fs);
    const float4 ab = *reinterpret_cast<const float4*>(att + fs + 4);
    v2f a0 = {aa.x, aa.y}, a1 = {aa.z, aa.w}, a2 = {ab.x, ab.y}, a3 = {ab.z, ab.w};

    float L = 0.f;
    v2f A0 = {0.f, 0.f}, A1 = {0.f, 0.f}, A2 = {0.f, 0.f}, A3 = {0.f, 0.f};

    const int p0 = rowstart[i], p1 = rowstart[i + 1];
    const char* xb = (const char*)xl + fs * 2;
    for (int p = p0 + 4 * half; p < p1; p += 8) {
        int j0 = csr_src[p];
        int j1 = csr_src[p + 1];   // pad-safe
        int j2 = csr_src[p + 2];
        int j3 = csr_src[p + 3];
        uint4 g0 = *reinterpret_cast<const uint4*>(xb + ((size_t)j0 << 9));
        uint4 g1 = *reinterpret_cast<const uint4*>(xb + ((size_t)j1 << 9));
        uint4 g2 = *reinterpret_cast<const uint4*>(xb + ((size_t)j2 << 9));
        uint4 g3 = *reinterpret_cast<const uint4*>(xb + ((size_t)j3 << 9));
        {
            v2f x0 = bf2_to_f2(g0.x), x1 = bf2_to_f2(g0.y), x2 = bf2_to_f2(g0.z), x3 = bf2_to_f2(g0.w);
            float e = red8(edot4(x0, x1, x2, x3, r0, r1, r2, r3, a0, a1, a2, a3));
            float pe = __expf(fminf(e, 60.f));      // p < p1 guaranteed
            L += pe;
            A0 += x0 * pe; A1 += x1 * pe; A2 += x2 * pe; A3 += x3 * pe;
        }
        {
            v2f x0 = bf2_to_f2(g1.x), x1 = bf2_to_f2(g1.y), x2 = bf2_to_f2(g1.z), x3 = bf2_to_f2(g1.w);
            float e = red8(edot4(x0, x1, x2, x3, r0, r1, r2, r3, a0, a1, a2, a3));
            float pe = (p + 1 < p1) ? __expf(fminf(e, 60.f)) : 0.f;
            L += pe;
            A0 += x0 * pe; A1 += x1 * pe; A2 += x2 * pe; A3 += x3 * pe;
        }
        {
            v2f x0 = bf2_to_f2(g2.x), x1 = bf2_to_f2(g2.y), x2 = bf2_to_f2(g2.z), x3 = bf2_to_f2(g2.w);
            float e = red8(edot4(x0, x1, x2, x3, r0, r1, r2, r3, a0, a1, a2, a3));
            float pe = (p + 2 < p1) ? __expf(fminf(e, 60.f)) : 0.f;
            L += pe;
            A0 += x0 * pe; A1 += x1 * pe; A2 += x2 * pe; A3 += x3 * pe;
        }
        {
            v2f x0 = bf2_to_f2(g3.x), x1 = bf2_to_f2(g3.y), x2 = bf2_to_f2(g3.z), x3 = bf2_to_f2(g3.w);
            float e = red8(edot4(x0, x1, x2, x3, r0, r1, r2, r3, a0, a1, a2, a3));
            float pe = (p + 3 < p1) ? __expf(fminf(e, 60.f)) : 0.f;
            L += pe;
            A0 += x0 * pe; A1 += x1 * pe; A2 += x2 * pe; A3 += x3 * pe;
        }
    }
    // combine the two edge-halves (lane bit 5)
    L += __shfl_xor(L, 32);
    float v[8] = {A0.x, A0.y, A1.x, A1.y, A2.x, A2.y, A3.x, A3.y};
    #pragma unroll
    for (int k = 0; k < 8; ++k) v[k] += __shfl_xor(v[k], 32);
    float inv = 1.f / (L + SM_EPS);
    #pragma unroll
    for (int k = 0; k < 8; ++k) {
        v[k] *= inv;                       // per-head alpha-normalized message
        v[k] += __shfl_xor(v[k], 8);       // sum over head bit 0
        v[k] += __shfl_xor(v[k], 16);      // sum over head bit 1
    }
    const int c0 = (lane & 7) * 8;
    const float4 b0 = *reinterpret_cast<const float4*>(bias + c0);
    const float4 b1 = *reinterpret_cast<const float4*>(bias + c0 + 4);
    float o[8];
    o[0] = v[0] * 0.25f + b0.x; o[1] = v[1] * 0.25f + b0.y;
    o[2] = v[2] * 0.25f + b0.z; o[3] = v[3] * 0.25f + b0.w;
    o[4] = v[4] * 0.25f + b1.x; o[5] = v[5] * 0.25f + b1.y;
    o[6] = v[6] * 0.25f + b1.z; o[7] = v[7] * 0.25f + b1.w;
    float psum = 0.f;
    #pragma unroll
    for (int k = 0; k < 8; ++k) psum += o[k];
    float mu = red8(psum) * 0.015625f;
    float d[8], vsum = 0.f;
    #pragma unroll
    for (int k = 0; k < 8; ++k) { d[k] = o[k] - mu; vsum += d[k] * d[k]; }
    float istd = rsqrtf(red8(vsum) * 0.015625f + LN_EPS);
    const float4 g0 = *reinterpret_cast<const float4*>(lng + c0);
    const float4 g1 = *reinterpret_cast<const float4*>(lng + c0 + 4);
    const float4 bb0 = *reinterpret_cast<const float4*>(lnb + c0);
    const float4 bb1 = *reinterpret_cast<const float4*>(lnb + c0 + 4);
    float h[8];
    h[0] = fmaxf(d[0] * istd * g0.x + bb0.x, 0.f);
    h[1] = fmaxf(d[1] * istd * g0.y + bb0.y, 0.f);
    h[2] = fmaxf(d[2] * istd * g0.z + bb0.z, 0.f);
    h[3] = fmaxf(d[3] * istd * g0.w + bb0.w, 0.f);
    h[4] = fmaxf(d[4] * istd * g1.x + bb1.x, 0.f);
    h[5] = fmaxf(d[5] * istd * g1.y + bb1.y, 0.f);
    h[6] = fmaxf(d[6] * istd * g1.z + bb1.z, 0.f);
    h[7] = fmaxf(d[7] * istd * g1.w + bb1.w, 0.f);
    if (lane < 8) {
        uint4 pk;
        pk.x = pack_bf2(h[0], h[1]);
        pk.y = pack_bf2(h[2], h[3]);
        pk.z = pack_bf2(h[4], h[5]);
        pk.w = pack_bf2(h[6], h[7]);
        *reinterpret_cast<uint4*>(h1b + (size_t)i * 64 + c0) = pk;
    }
}

// ---------------- layer 2: one node per wave; 8 lanes/edge, 8 edges in flight ---
__global__ void __launch_bounds__(64) k_node2(
                        const __hip_bfloat16* __restrict__ xl,
                        const __hip_bfloat16* __restrict__ xr,
                        const int* __restrict__ rowstart,
                        const unsigned short* __restrict__ csr_src,
                        const float* __restrict__ att,   // [64]
                        const float* __restrict__ bias,
                        const float* __restrict__ lng,
                        const float* __restrict__ lnb,
                        float* __restrict__ out) {
    const int i = blockIdx.x;
    const int lane = threadIdx.x;
    const int es = lane >> 3;            // edge slot 0..7
    const int fs = (lane & 7) * 8;       // feature slice

    uint4 rr = *reinterpret_cast<const uint4*>(xr + (size_t)i * 64 + fs);
    v2f r0 = bf2_to_f2(rr.x), r1 = bf2_to_f2(rr.y),
        r2 = bf2_to_f2(rr.z), r3 = bf2_to_f2(rr.w);
    const float4 aa = *reinterpret_cast<const float4*>(att + fs);
    const float4 ab = *reinterpret_cast<const float4*>(att + fs + 4);
    v2f a0 = {aa.x, aa.y}, a1 = {aa.z, aa.w}, a2 = {ab.x, ab.y}, a3 = {ab.z, ab.w};

    float L = 0.f;
    v2f A0 = {0.f, 0.f}, A1 = {0.f, 0.f}, A2 = {0.f, 0.f}, A3 = {0.f, 0.f};

    const char* xb = (const char*)xl + fs * 2;
    const int p0 = rowstart[i], p1 = rowstart[i + 1];
    for (int p = p0; p < p1; p += 8) {
        int pe_i = p + es;
        int j = csr_src[pe_i];                          // pad-safe
        uint4 g = *reinterpret_cast<const uint4*>(xb + ((size_t)j << 7));
        v2f x0 = bf2_to_f2(g.x), x1 = bf2_to_f2(g.y), x2 = bf2_to_f2(g.z), x3 = bf2_to_f2(g.w);
        float e = red8(edot4(x0, x1, x2, x3, r0, r1, r2, r3, a0, a1, a2, a3));
        float w = (pe_i < p1) ? __expf(fminf(e, 60.f)) : 0.f;
        L += w;
        A0 += x0 * w; A1 += x1 * w; A2 += x2 * w; A3 += x3 * w;
    }
    // reduce across the 8 edge slots (lane bits 3,4,5)
    float v[8] = {A0.x, A0.y, A1.x, A1.y, A2.x, A2.y, A3.x, A3.y};
    #pragma unroll
    for (int s = 8; s <= 32; s <<= 1) {
        L += __shfl_xor(L, s);
        #pragma unroll
        for (int k = 0; k < 8; ++k) v[k] += __shfl_xor(v[k], s);
    }
    float inv = 1.f / (L + SM_EPS);
    const float4 b0 = *reinterpret_cast<const float4*>(bias + fs);
    const float4 b1 = *reinterpret_cast<const float4*>(bias + fs + 4);
    float o[8];
    o[0] = v[0] * inv + b0.x; o[1] = v[1] * inv + b0.y;
    o[2] = v[2] * inv + b0.z; o[3] = v[3] * inv + b0.w;
    o[4] = v[4] * inv + b1.x; o[5] = v[5] * inv + b1.y;
    o[6] = v[6] * inv + b1.z; o[7] = v[7] * inv + b1.w;
    float psum = 0.f;
    #pragma unroll
    for (int k = 0; k < 8; ++k) psum += o[k];
    float mu = red8(psum) * 0.015625f;
    float d[8], vsum = 0.f;
    #pragma unroll
    for (int k = 0; k < 8; ++k) { d[k] = o[k] - mu; vsum += d[k] * d[k]; }
    float istd = rsqrtf(red8(vsum) * 0.015625f + LN_EPS);
    const float4 g0 = *reinterpret_cast<const float4*>(lng + fs);
    const float4 g1 = *reinterpret_cast<const float4*>(lng + fs + 4);
    const float4 bb0 = *reinterpret_cast<const float4*>(lnb + fs);
    const float4 bb1 = *reinterpret_cast<const float4*>(lnb + fs + 4);
    if (lane < 8) {
        float4 y0, y1;
        y0.x = d[0] * istd * g0.x + bb0.x;
        y0.y = d[1] * istd * g0.y + bb0.y;
        y0.z = d[2] * istd * g0.z + bb0.z;
        y0.w = d[3] * istd * g0.w + bb0.w;
        y1.x = d[4] * istd * g1.x + bb1.x;
        y1.y = d[5] * istd * g1.y + bb1.y;
        y1.z = d[6] * istd * g1.z + bb1.z;
        y1.w = d[7] * istd * g1.w + bb1.w;
        *reinterpret_cast<float4*>(out + (size_t)i * 64 + fs) = y0;
        *reinterpret_cast<float4*>(out + (size_t)i * 64 + fs + 4) = y1;
    }
}

extern "C" void kernel_launch(void* const* d_in, const int* in_sizes, int n_in,
                              void* d_out, int out_size, void* d_ws, size_t ws_size,
                              hipStream_t stream) {
    const float* x    = (const float*)d_in[0];
    const int*   ei   = (const int*)d_in[1];
    const float* W1l  = (const float*)d_in[2];
    const float* W1r  = (const float*)d_in[3];
    const float* att1 = (const float*)d_in[4];
    const float* b1   = (const float*)d_in[5];
    const float* ln1g = (const float*)d_in[6];
    const float* ln1b = (const float*)d_in[7];
    const float* W2l  = (const float*)d_in[8];
    const float* W2r  = (const float*)d_in[9];
    const float* att2 = (const float*)d_in[10];
    const float* b2   = (const float*)d_in[11];
    const float* ln2g = (const float*)d_in[12];
    const float* ln2b = (const float*)d_in[13];
    float* out = (float*)d_out;

    char* w = (char*)d_ws;
    size_t off = 0;
    auto alloc = [&](size_t bytes) -> void* {
        void* p = w + off;
        off += (bytes + 255) & ~(size_t)255;
        return p;
    };
    __hip_bfloat16* xl1  = (__hip_bfloat16*)alloc((size_t)NNODES * 256 * 2);
    __hip_bfloat16* xr1  = (__hip_bfloat16*)alloc((size_t)NNODES * 256 * 2);
    __hip_bfloat16* h1b  = (__hip_bfloat16*)alloc((size_t)NNODES * 64 * 2);
    __hip_bfloat16* xl2  = (__hip_bfloat16*)alloc((size_t)NNODES * 64 * 2);
    __hip_bfloat16* xr2  = (__hip_bfloat16*)alloc((size_t)NNODES * 64 * 2);
    __hip_bfloat16* w1lT = (__hip_bfloat16*)alloc(256 * 256 * 2);
    __hip_bfloat16* w1rT = (__hip_bfloat16*)alloc(256 * 256 * 2);
    __hip_bfloat16* w2lT = (__hip_bfloat16*)alloc(64 * 64 * 2);
    __hip_bfloat16* w2rT = (__hip_bfloat16*)alloc(64 * 64 * 2);
    int* part     = (int*)alloc((size_t)256 * NBLK * 4);       // per-(bucket,block)
    unsigned* pairs = (unsigned*)alloc((size_t)ETOT * 4);
    int* rowstart = (int*)alloc((size_t)(NNODES + 1) * 4);
    unsigned short* csr_src = (unsigned short*)alloc((size_t)(ETOT + 16) * 2);
    int* blocksum = (int*)alloc(1024);
    (void)ws_size; (void)in_sizes; (void)n_in; (void)out_size;

    k_cast_w<<<544, 256, 0, stream>>>(W1l, W1r, W2l, W2r,
                                      w1lT, w1rT, w2lT, w2rT, csr_src, rowstart);

    // ---- CSR build: bucket sort (196 buckets of 256 nodes), zero global atomics
    k_bhist<<<NBLK, 256, 0, stream>>>(ei, part);
    const int partN = 256 * NBLK;                       // 53248
    k_scan_blk<<<partN / 256, 256, 0, stream>>>(part, partN, part, blocksum);
    k_scan_top<<<1, 256, 0, stream>>>(blocksum, partN / 256);
    k_scan_add<<<partN / 256, 256, 0, stream>>>(part, blocksum, partN);
    k_bscatter<<<NBLK, 256, 0, stream>>>(ei, part, pairs);
    k_nfinal<<<NBUCK, 256, 0, stream>>>(pairs, part, rowstart, csr_src);

    // ---- dense pipeline
    const int gm = (NNODES + 63) / 64;                  // 782
    k_gemm_x1<<<gm, 256, 0, stream>>>(x, w1lT, w1rT, xl1, xr1, NNODES);
    k_node1<<<NNODES, 64, 0, stream>>>(xl1, xr1, rowstart, csr_src,
                                       att1, b1, ln1g, ln1b, h1b);
    k_gemm_dual<<<gm, 256, 0, stream>>>(h1b, w2lT, w2rT, xl2, xr2, NNODES);
    k_node2<<<NNODES, 64, 0, stream>>>(xl2, xr2, rowstart, csr_src,
                                       att2, b2, ln2g, ln2b, out);
}

// Round 6
// 282.584 us; speedup vs baseline: 1.2144x; 1.2144x over previous
//
#include <hip/hip_runtime.h>
#include <hip/hip_bf16.h>

#define NNODES 50000
#define NEDGES 800000
#define ETOT   850000
#define NEG_SLOPE 0.2f
#define LN_EPS 1e-5f
#define SM_EPS 1e-16f
#define NBUCK 196                 // ceil(50000/256) buckets of 256 nodes
#define NBLK 208                  // ceil(850000/4096) edge chunks
#define CHUNK 4096

typedef short bf16x8 __attribute__((ext_vector_type(8)));
typedef float f32x4  __attribute__((ext_vector_type(4)));
typedef float v2f    __attribute__((ext_vector_type(2)));

__device__ __forceinline__ unsigned pack_bf2(float a, float b) {
    __hip_bfloat162 p;
    p.x = __float2bfloat16(a);
    p.y = __float2bfloat16(b);
    return *reinterpret_cast<unsigned*>(&p);
}

__device__ __forceinline__ v2f bf2_to_f2(unsigned u) {
    v2f r;
    r.x = __int_as_float((int)(u << 16));
    r.y = __int_as_float((int)(u & 0xFFFF0000u));
    return r;
}

template <int CTRL>
__device__ __forceinline__ float dpp_add(float x) {
    return x + __int_as_float(__builtin_amdgcn_update_dpp(
        0, __float_as_int(x), CTRL, 0xF, 0xF, true));
}
// sum over aligned 8-lane group, result in all 8 lanes
__device__ __forceinline__ float red8(float x) {
    x = dpp_add<0xB1>(x);
    x = dpp_add<0x4E>(x);
    x = dpp_add<0x141>(x);
    return x;
}

// per-lane partial of att-dot over 8 features
__device__ __forceinline__ float edot4(v2f x0, v2f x1, v2f x2, v2f x3,
                                       v2f r0, v2f r1, v2f r2, v2f r3,
                                       v2f a0, v2f a1, v2f a2, v2f a3) {
    v2f s0 = x0 + r0, s1 = x1 + r1, s2 = x2 + r2, s3 = x3 + r3;
    v2f t0 = __builtin_elementwise_max(s0, s0 * NEG_SLOPE);
    v2f t1 = __builtin_elementwise_max(s1, s1 * NEG_SLOPE);
    v2f t2 = __builtin_elementwise_max(s2, s2 * NEG_SLOPE);
    v2f t3 = __builtin_elementwise_max(s3, s3 * NEG_SLOPE);
    v2f d = t0 * a0 + t1 * a1 + t2 * a2 + t3 * a3;
    return d.x + d.y;
}

// XOR-swizzled LDS offset for 64-col short tiles (16B granules)
__device__ __forceinline__ int sw(int row, int c8) {
    return (row << 6) + ((c8 ^ (row & 7)) << 3);
}

// ---------------- weights cast + csr pad + sentinel (tiny) ----------------
__global__ void k_cast_w(const float* __restrict__ W1l, const float* __restrict__ W1r,
                         const float* __restrict__ W2l, const float* __restrict__ W2r,
                         __hip_bfloat16* __restrict__ w1lT, __hip_bfloat16* __restrict__ w1rT,
                         __hip_bfloat16* __restrict__ w2lT, __hip_bfloat16* __restrict__ w2rT,
                         unsigned short* __restrict__ csr_src, int* __restrict__ rowstart) {
    int t = blockIdx.x * 256 + threadIdx.x;
    if (t < 16) csr_src[ETOT + t] = 0;       // pad: node-0 reads, weight-masked
    if (t == 16) rowstart[NNODES] = ETOT;    // sentinel
    if (t < 65536) {
        int k = t >> 8, n = t & 255;
        w1lT[n * 256 + k] = __float2bfloat16(W1l[t]);
    } else if (t < 131072) {
        int u = t - 65536; int k = u >> 8, n = u & 255;
        w1rT[n * 256 + k] = __float2bfloat16(W1r[u]);
    } else if (t < 135168) {
        int u = t - 131072; int k = u >> 6, n = u & 63;
        w2lT[n * 64 + k] = __float2bfloat16(W2l[u]);
    } else if (t < 139264) {
        int u = t - 135168; int k = u >> 6, n = u & 63;
        w2rT[n * 64 + k] = __float2bfloat16(W2r[u]);
    }
}

// ---------------- bucket histogram: LDS only, per-(bucket,block) counts ----------
__global__ void __launch_bounds__(256) k_bhist(const int* __restrict__ ei,
                                               int* __restrict__ part) {
    __shared__ int h[256];
    h[threadIdx.x] = 0;
    __syncthreads();
    const int base = blockIdx.x * CHUNK;
    #pragma unroll
    for (int it = 0; it < 16; ++it) {
        int e = base + it * 256 + threadIdx.x;
        if (e < ETOT) {
            int dst = (e < NEDGES) ? ei[NEDGES + e] : (e - NEDGES);
            atomicAdd(&h[dst >> 8], 1);
        }
    }
    __syncthreads();
    part[threadIdx.x * NBLK + blockIdx.x] = h[threadIdx.x];   // bucket-major
}

// ---------------- generic block-level exclusive scan ----------------
__global__ void k_scan_blk(const int* __restrict__ in, int n,
                           int* __restrict__ out, int* __restrict__ bsum) {
    __shared__ int s[256];
    int t = threadIdx.x;
    int i = blockIdx.x * 256 + t;
    int v = (i < n) ? in[i] : 0;
    s[t] = v;
    __syncthreads();
    #pragma unroll
    for (int off = 1; off < 256; off <<= 1) {
        int add = (t >= off) ? s[t - off] : 0;
        __syncthreads();
        s[t] += add;
        __syncthreads();
    }
    if (i < n) out[i] = s[t] - v;
    if (t == 255) bsum[blockIdx.x] = s[255];
}

__global__ void k_scan_top(int* __restrict__ bs, int nb) {   // nb <= 256
    __shared__ int s[256];
    int t = threadIdx.x;
    int v = (t < nb) ? bs[t] : 0;
    s[t] = v;
    __syncthreads();
    #pragma unroll
    for (int off = 1; off < 256; off <<= 1) {
        int add = (t >= off) ? s[t - off] : 0;
        __syncthreads();
        s[t] += add;
        __syncthreads();
    }
    if (t < nb) bs[t] = s[t] - v;
}

__global__ void k_scan_add(int* __restrict__ out, const int* __restrict__ bs, int n) {
    int i = blockIdx.x * 256 + threadIdx.x;
    if (i < n) out[i] += bs[i >> 8];
}

// ---------------- bucket scatter: LDS cursors, coalesced-run pair writes --------
__global__ void __launch_bounds__(256) k_bscatter(const int* __restrict__ ei,
                                                  const int* __restrict__ partoff,
                                                  unsigned* __restrict__ pairs) {
    __shared__ int cnt[256];
    const int t = threadIdx.x;
    cnt[t] = partoff[t * NBLK + blockIdx.x];
    __syncthreads();
    const int base = blockIdx.x * CHUNK;
    #pragma unroll
    for (int it = 0; it < 16; ++it) {
        int e = base + it * 256 + t;
        if (e < ETOT) {
            int dst, src;
            if (e < NEDGES) { dst = ei[NEDGES + e]; src = ei[e]; }
            else            { dst = e - NEDGES;     src = dst; }
            int pos = atomicAdd(&cnt[dst >> 8], 1);
            pairs[pos] = ((unsigned)dst << 16) | (unsigned)src;
        }
    }
}

// ---------------- fused per-bucket: count + LDS scan + rowstart + scatter -------
__global__ void __launch_bounds__(256) k_nfinal(const unsigned* __restrict__ pairs,
                                                const int* __restrict__ partoff,
                                                int* __restrict__ rowstart,
                                                unsigned short* __restrict__ csr_src) {
    __shared__ int h[256];
    __shared__ int cur[256];
    const int b = blockIdx.x;
    const int t = threadIdx.x;
    const int r0 = partoff[b * NBLK];
    const int r1 = partoff[(b + 1) * NBLK];
    h[t] = 0;
    __syncthreads();
    for (int i = r0 + t; i < r1; i += 1024) {
        unsigned p0 = pairs[i];
        bool v1 = (i + 256 < r1), v2 = (i + 512 < r1), v3 = (i + 768 < r1);
        unsigned p1 = v1 ? pairs[i + 256] : 0u;
        unsigned p2 = v2 ? pairs[i + 512] : 0u;
        unsigned p3 = v3 ? pairs[i + 768] : 0u;
        atomicAdd(&h[(p0 >> 16) & 255], 1);
        if (v1) atomicAdd(&h[(p1 >> 16) & 255], 1);
        if (v2) atomicAdd(&h[(p2 >> 16) & 255], 1);
        if (v3) atomicAdd(&h[(p3 >> 16) & 255], 1);
    }
    __syncthreads();
    int v = h[t];
    cur[t] = v;
    __syncthreads();
    #pragma unroll
    for (int off = 1; off < 256; off <<= 1) {
        int add = (t >= off) ? cur[t - off] : 0;
        __syncthreads();
        cur[t] += add;
        __syncthreads();
    }
    int start = r0 + cur[t] - v;
    int node = (b << 8) + t;
    if (node < NNODES) rowstart[node] = start;
    cur[t] = start;
    __syncthreads();
    for (int i = r0 + t; i < r1; i += 1024) {
        unsigned p0 = pairs[i];
        bool v1 = (i + 256 < r1), v2 = (i + 512 < r1), v3 = (i + 768 < r1);
        unsigned p1 = v1 ? pairs[i + 256] : 0u;
        unsigned p2 = v2 ? pairs[i + 512] : 0u;
        unsigned p3 = v3 ? pairs[i + 768] : 0u;
        int q0 = atomicAdd(&cur[(p0 >> 16) & 255], 1);
        csr_src[q0] = (unsigned short)(p0 & 0xFFFFu);
        if (v1) { int q = atomicAdd(&cur[(p1 >> 16) & 255], 1); csr_src[q] = (unsigned short)(p1 & 0xFFFFu); }
        if (v2) { int q = atomicAdd(&cur[(p2 >> 16) & 255], 1); csr_src[q] = (unsigned short)(p2 & 0xFFFFu); }
        if (v3) { int q = atomicAdd(&cur[(p3 >> 16) & 255], 1); csr_src[q] = (unsigned short)(p3 & 0xFFFFu); }
    }
}

// ---------------- layer-1 GEMM: f32 A cast in-stage, 2 n-slices/block ----------
// grid (ceil(M/64), 2). LDS = 8KB A + 32KB B = 40KB -> 4 blocks/CU (16 waves),
// A read twice (2nd pass L3-hit); acc = 64 VGPR. Round-5 lesson: 72KB LDS
// single-pass was an occupancy cliff (8%, latency-bound, 106 us).
__global__ __launch_bounds__(256) void k_gemm_x1(
    const float* __restrict__ X,
    const __hip_bfloat16* __restrict__ WTl,
    const __hip_bfloat16* __restrict__ WTr,
    __hip_bfloat16* __restrict__ Cl,
    __hip_bfloat16* __restrict__ Cr, int M)
{
    __shared__ short As[64 * 64];
    __shared__ short Bls[2][64 * 64];
    __shared__ short Brs[2][64 * 64];
    const int t = threadIdx.x;
    const int m0 = blockIdx.x * 64;
    const int nb = blockIdx.y * 128;     // n-slice base
    const int wave = t >> 6, lane = t & 63;
    const int wm = wave & 1, wn = wave >> 1;
    const int l15 = lane & 15, quad = lane >> 4;

    f32x4 accl[2][2][2] = {};
    f32x4 accr[2][2][2] = {};
    for (int k0 = 0; k0 < 256; k0 += 64) {
        __syncthreads();
        #pragma unroll
        for (int it = 0; it < 2; ++it) {
            int f = t + 256 * it;
            int r = f >> 3, c8 = f & 7;
            int row = m0 + r;
            uint4 v = make_uint4(0u, 0u, 0u, 0u);
            if (row < M) {
                const float4* src = reinterpret_cast<const float4*>(
                    X + (size_t)row * 256 + k0 + c8 * 8);
                float4 a = src[0], b = src[1];
                v.x = pack_bf2(a.x, a.y);
                v.y = pack_bf2(a.z, a.w);
                v.z = pack_bf2(b.x, b.y);
                v.w = pack_bf2(b.z, b.w);
            }
            *reinterpret_cast<uint4*>(&As[sw(r, c8)]) = v;
        }
        #pragma unroll
        for (int it = 0; it < 4; ++it) {
            int f = t + 256 * it;                 // 0..1023
            int s = f >> 9, ws = f & 511;
            int n = ws >> 3, c8 = ws & 7;
            int ng = nb + s * 64 + n;
            *reinterpret_cast<uint4*>(&Bls[s][sw(n, c8)]) =
                *reinterpret_cast<const uint4*>(&WTl[(size_t)ng * 256 + k0 + c8 * 8]);
            *reinterpret_cast<uint4*>(&Brs[s][sw(n, c8)]) =
                *reinterpret_cast<const uint4*>(&WTr[(size_t)ng * 256 + k0 + c8 * 8]);
        }
        __syncthreads();
        #pragma unroll
        for (int kk8 = 0; kk8 < 8; kk8 += 4) {
            bf16x8 af[2];
            #pragma unroll
            for (int mi = 0; mi < 2; ++mi)
                af[mi] = *reinterpret_cast<const bf16x8*>(
                    &As[sw(wm * 32 + mi * 16 + l15, kk8 + quad)]);
            #pragma unroll
            for (int s = 0; s < 2; ++s) {
                bf16x8 bl[2], br[2];
                #pragma unroll
                for (int ni = 0; ni < 2; ++ni) {
                    int rB = wn * 32 + ni * 16 + l15;
                    bl[ni] = *reinterpret_cast<const bf16x8*>(&Bls[s][sw(rB, kk8 + quad)]);
                    br[ni] = *reinterpret_cast<const bf16x8*>(&Brs[s][sw(rB, kk8 + quad)]);
                }
                #pragma unroll
                for (int mi = 0; mi < 2; ++mi)
                    #pragma unroll
                    for (int ni = 0; ni < 2; ++ni) {
                        accl[s][mi][ni] = __builtin_amdgcn_mfma_f32_16x16x32_bf16(
                            af[mi], bl[ni], accl[s][mi][ni], 0, 0, 0);
                        accr[s][mi][ni] = __builtin_amdgcn_mfma_f32_16x16x32_bf16(
                            af[mi], br[ni], accr[s][mi][ni], 0, 0, 0);
                    }
            }
        }
    }
    #pragma unroll
    for (int s = 0; s < 2; ++s)
        #pragma unroll
        for (int mi = 0; mi < 2; ++mi)
            #pragma unroll
            for (int ni = 0; ni < 2; ++ni)
                #pragma unroll
                for (int r = 0; r < 4; ++r) {
                    int row = m0 + wm * 32 + mi * 16 + quad * 4 + r;
                    int col = nb + s * 64 + wn * 32 + ni * 16 + l15;
                    if (row < M) {
                        Cl[(size_t)row * 256 + col] = __float2bfloat16(accl[s][mi][ni][r]);
                        Cr[(size_t)row * 256 + col] = __float2bfloat16(accr[s][mi][ni][r]);
                    }
                }
}

// ---------------- layer-2 GEMM (bf16 A, N=64) -----------------------------------
__global__ __launch_bounds__(256) void k_gemm_dual(
    const __hip_bfloat16* __restrict__ A,
    const __hip_bfloat16* __restrict__ WTl,
    const __hip_bfloat16* __restrict__ WTr,
    __hip_bfloat16* __restrict__ Cl,
    __hip_bfloat16* __restrict__ Cr, int M)
{
    __shared__ short As[64 * 64];
    __shared__ short Bls[64 * 64];
    __shared__ short Brs[64 * 64];
    const int t = threadIdx.x;
    const int m0 = blockIdx.x * 64;
    const int wave = t >> 6, lane = t & 63;
    const int wm = wave & 1, wn = wave >> 1;
    const int l15 = lane & 15, quad = lane >> 4;

    f32x4 accl[2][2] = {};
    f32x4 accr[2][2] = {};
    {
        #pragma unroll
        for (int it = 0; it < 2; ++it) {
            int f = t + 256 * it;
            int r = f >> 3, c8 = f & 7;
            int row = m0 + r;
            uint4 v = make_uint4(0u, 0u, 0u, 0u);
            if (row < M) v = *reinterpret_cast<const uint4*>(&A[(size_t)row * 64 + c8 * 8]);
            *reinterpret_cast<uint4*>(&As[sw(r, c8)]) = v;
        }
        #pragma unroll
        for (int it = 0; it < 2; ++it) {
            int f = t + 256 * it;
            int n = f >> 3, c8 = f & 7;
            *reinterpret_cast<uint4*>(&Bls[sw(n, c8)]) =
                *reinterpret_cast<const uint4*>(&WTl[(size_t)n * 64 + c8 * 8]);
            *reinterpret_cast<uint4*>(&Brs[sw(n, c8)]) =
                *reinterpret_cast<const uint4*>(&WTr[(size_t)n * 64 + c8 * 8]);
        }
        __syncthreads();
        #pragma unroll
        for (int kk8 = 0; kk8 < 8; kk8 += 4) {
            bf16x8 af[2], bl[2], br[2];
            #pragma unroll
            for (int mi = 0; mi < 2; ++mi)
                af[mi] = *reinterpret_cast<const bf16x8*>(
                    &As[sw(wm * 32 + mi * 16 + l15, kk8 + quad)]);
            #pragma unroll
            for (int ni = 0; ni < 2; ++ni) {
                int rB = wn * 32 + ni * 16 + l15;
                bl[ni] = *reinterpret_cast<const bf16x8*>(&Bls[sw(rB, kk8 + quad)]);
                br[ni] = *reinterpret_cast<const bf16x8*>(&Brs[sw(rB, kk8 + quad)]);
            }
            #pragma unroll
            for (int mi = 0; mi < 2; ++mi)
                #pragma unroll
                for (int ni = 0; ni < 2; ++ni) {
                    accl[mi][ni] = __builtin_amdgcn_mfma_f32_16x16x32_bf16(
                        af[mi], bl[ni], accl[mi][ni], 0, 0, 0);
                    accr[mi][ni] = __builtin_amdgcn_mfma_f32_16x16x32_bf16(
                        af[mi], br[ni], accr[mi][ni], 0, 0, 0);
                }
        }
    }
    #pragma unroll
    for (int mi = 0; mi < 2; ++mi)
        #pragma unroll
        for (int ni = 0; ni < 2; ++ni)
            #pragma unroll
            for (int r = 0; r < 4; ++r) {
                int row = m0 + wm * 32 + mi * 16 + quad * 4 + r;
                int col = wn * 32 + ni * 16 + l15;
                if (row < M) {
                    Cl[(size_t)row * 64 + col] = __float2bfloat16(accl[mi][ni][r]);
                    Cr[(size_t)row * 64 + col] = __float2bfloat16(accr[mi][ni][r]);
                }
            }
}

// ---------------- layer 1: one node per wave; 16B gathers, 8 edges in flight ----
__global__ void __launch_bounds__(64) k_node1(
                        const __hip_bfloat16* __restrict__ xl,
                        const __hip_bfloat16* __restrict__ xr,
                        const int* __restrict__ rowstart,
                        const unsigned short* __restrict__ csr_src,
                        const float* __restrict__ att,   // [4,64]
                        const float* __restrict__ bias,  // [64]
                        const float* __restrict__ lng,
                        const float* __restrict__ lnb,
                        __hip_bfloat16* __restrict__ h1b) {
    const int i = blockIdx.x;
    const int lane = threadIdx.x;
    const int half = lane >> 5;
    const int fs = (lane & 31) * 8;      // feature slice

    uint4 rr = *reinterpret_cast<const uint4*>(xr + (size_t)i * 256 + fs);
    v2f r0 = bf2_to_f2(rr.x), r1 = bf2_to_f2(rr.y),
        r2 = bf2_to_f2(rr.z), r3 = bf2_to_f2(rr.w);
    const float4 aa = *reinterpret_cast<const float4*>(att + fs);
    const float4 ab = *reinterpret_cast<const float4*>(att + fs + 4);
    v2f a0 = {aa.x, aa.y}, a1 = {aa.z, aa.w}, a2 = {ab.x, ab.y}, a3 = {ab.z, ab.w};

    float L = 0.f;
    v2f A0 = {0.f, 0.f}, A1 = {0.f, 0.f}, A2 = {0.f, 0.f}, A3 = {0.f, 0.f};

    const int p0 = rowstart[i], p1 = rowstart[i + 1];
    const char* xb = (const char*)xl + fs * 2;
    for (int p = p0 + 4 * half; p < p1; p += 8) {
        int j0 = csr_src[p];
        int j1 = csr_src[p + 1];   // pad-safe
        int j2 = csr_src[p + 2];
        int j3 = csr_src[p + 3];
        uint4 g0 = *reinterpret_cast<const uint4*>(xb + ((size_t)j0 << 9));
        uint4 g1 = *reinterpret_cast<const uint4*>(xb + ((size_t)j1 << 9));
        uint4 g2 = *reinterpret_cast<const uint4*>(xb + ((size_t)j2 << 9));
        uint4 g3 = *reinterpret_cast<const uint4*>(xb + ((size_t)j3 << 9));
        {
            v2f x0 = bf2_to_f2(g0.x), x1 = bf2_to_f2(g0.y), x2 = bf2_to_f2(g0.z), x3 = bf2_to_f2(g0.w);
            float e = red8(edot4(x0, x1, x2, x3, r0, r1, r2, r3, a0, a1, a2, a3));
            float pe = __expf(fminf(e, 60.f));      // p < p1 guaranteed
            L += pe;
            A0 += x0 * pe; A1 += x1 * pe; A2 += x2 * pe; A3 += x3 * pe;
        }
        {
            v2f x0 = bf2_to_f2(g1.x), x1 = bf2_to_f2(g1.y), x2 = bf2_to_f2(g1.z), x3 = bf2_to_f2(g1.w);
            float e = red8(edot4(x0, x1, x2, x3, r0, r1, r2, r3, a0, a1, a2, a3));
            float pe = (p + 1 < p1) ? __expf(fminf(e, 60.f)) : 0.f;
            L += pe;
            A0 += x0 * pe; A1 += x1 * pe; A2 += x2 * pe; A3 += x3 * pe;
        }
        {
            v2f x0 = bf2_to_f2(g2.x), x1 = bf2_to_f2(g2.y), x2 = bf2_to_f2(g2.z), x3 = bf2_to_f2(g2.w);
            float e = red8(edot4(x0, x1, x2, x3, r0, r1, r2, r3, a0, a1, a2, a3));
            float pe = (p + 2 < p1) ? __expf(fminf(e, 60.f)) : 0.f;
            L += pe;
            A0 += x0 * pe; A1 += x1 * pe; A2 += x2 * pe; A3 += x3 * pe;
        }
        {
            v2f x0 = bf2_to_f2(g3.x), x1 = bf2_to_f2(g3.y), x2 = bf2_to_f2(g3.z), x3 = bf2_to_f2(g3.w);
            float e = red8(edot4(x0, x1, x2, x3, r0, r1, r2, r3, a0, a1, a2, a3));
            float pe = (p + 3 < p1) ? __expf(fminf(e, 60.f)) : 0.f;
            L += pe;
            A0 += x0 * pe; A1 += x1 * pe; A2 += x2 * pe; A3 += x3 * pe;
        }
    }
    // combine the two edge-halves (lane bit 5)
    L += __shfl_xor(L, 32);
    float v[8] = {A0.x, A0.y, A1.x, A1.y, A2.x, A2.y, A3.x, A3.y};
    #pragma unroll
    for (int k = 0; k < 8; ++k) v[k] += __shfl_xor(v[k], 32);
    float inv = 1.f / (L + SM_EPS);
    #pragma unroll
    for (int k = 0; k < 8; ++k) {
        v[k] *= inv;                       // per-head alpha-normalized message
        v[k] += __shfl_xor(v[k], 8);       // sum over head bit 0
        v[k] += __shfl_xor(v[k], 16);      // sum over head bit 1
    }
    const int c0 = (lane & 7) * 8;
    const float4 b0 = *reinterpret_cast<const float4*>(bias + c0);
    const float4 b1 = *reinterpret_cast<const float4*>(bias + c0 + 4);
    float o[8];
    o[0] = v[0] * 0.25f + b0.x; o[1] = v[1] * 0.25f + b0.y;
    o[2] = v[2] * 0.25f + b0.z; o[3] = v[3] * 0.25f + b0.w;
    o[4] = v[4] * 0.25f + b1.x; o[5] = v[5] * 0.25f + b1.y;
    o[6] = v[6] * 0.25f + b1.z; o[7] = v[7] * 0.25f + b1.w;
    float psum = 0.f;
    #pragma unroll
    for (int k = 0; k < 8; ++k) psum += o[k];
    float mu = red8(psum) * 0.015625f;
    float d[8], vsum = 0.f;
    #pragma unroll
    for (int k = 0; k < 8; ++k) { d[k] = o[k] - mu; vsum += d[k] * d[k]; }
    float istd = rsqrtf(red8(vsum) * 0.015625f + LN_EPS);
    const float4 g0 = *reinterpret_cast<const float4*>(lng + c0);
    const float4 g1 = *reinterpret_cast<const float4*>(lng + c0 + 4);
    const float4 bb0 = *reinterpret_cast<const float4*>(lnb + c0);
    const float4 bb1 = *reinterpret_cast<const float4*>(lnb + c0 + 4);
    float h[8];
    h[0] = fmaxf(d[0] * istd * g0.x + bb0.x, 0.f);
    h[1] = fmaxf(d[1] * istd * g0.y + bb0.y, 0.f);
    h[2] = fmaxf(d[2] * istd * g0.z + bb0.z, 0.f);
    h[3] = fmaxf(d[3] * istd * g0.w + bb0.w, 0.f);
    h[4] = fmaxf(d[4] * istd * g1.x + bb1.x, 0.f);
    h[5] = fmaxf(d[5] * istd * g1.y + bb1.y, 0.f);
    h[6] = fmaxf(d[6] * istd * g1.z + bb1.z, 0.f);
    h[7] = fmaxf(d[7] * istd * g1.w + bb1.w, 0.f);
    if (lane < 8) {
        uint4 pk;
        pk.x = pack_bf2(h[0], h[1]);
        pk.y = pack_bf2(h[2], h[3]);
        pk.z = pack_bf2(h[4], h[5]);
        pk.w = pack_bf2(h[6], h[7]);
        *reinterpret_cast<uint4*>(h1b + (size_t)i * 64 + c0) = pk;
    }
}

// ---------------- layer 2: one node per wave; 8 lanes/edge, 8 edges in flight ---
__global__ void __launch_bounds__(64) k_node2(
                        const __hip_bfloat16* __restrict__ xl,
                        const __hip_bfloat16* __restrict__ xr,
                        const int* __restrict__ rowstart,
                        const unsigned short* __restrict__ csr_src,
                        const float* __restrict__ att,   // [64]
                        const float* __restrict__ bias,
                        const float* __restrict__ lng,
                        const float* __restrict__ lnb,
                        float* __restrict__ out) {
    const int i = blockIdx.x;
    const int lane = threadIdx.x;
    const int es = lane >> 3;            // edge slot 0..7
    const int fs = (lane & 7) * 8;       // feature slice

    uint4 rr = *reinterpret_cast<const uint4*>(xr + (size_t)i * 64 + fs);
    v2f r0 = bf2_to_f2(rr.x), r1 = bf2_to_f2(rr.y),
        r2 = bf2_to_f2(rr.z), r3 = bf2_to_f2(rr.w);
    const float4 aa = *reinterpret_cast<const float4*>(att + fs);
    const float4 ab = *reinterpret_cast<const float4*>(att + fs + 4);
    v2f a0 = {aa.x, aa.y}, a1 = {aa.z, aa.w}, a2 = {ab.x, ab.y}, a3 = {ab.z, ab.w};

    float L = 0.f;
    v2f A0 = {0.f, 0.f}, A1 = {0.f, 0.f}, A2 = {0.f, 0.f}, A3 = {0.f, 0.f};

    const char* xb = (const char*)xl + fs * 2;
    const int p0 = rowstart[i], p1 = rowstart[i + 1];
    for (int p = p0; p < p1; p += 8) {
        int pe_i = p + es;
        int j = csr_src[pe_i];                          // pad-safe
        uint4 g = *reinterpret_cast<const uint4*>(xb + ((size_t)j << 7));
        v2f x0 = bf2_to_f2(g.x), x1 = bf2_to_f2(g.y), x2 = bf2_to_f2(g.z), x3 = bf2_to_f2(g.w);
        float e = red8(edot4(x0, x1, x2, x3, r0, r1, r2, r3, a0, a1, a2, a3));
        float w = (pe_i < p1) ? __expf(fminf(e, 60.f)) : 0.f;
        L += w;
        A0 += x0 * w; A1 += x1 * w; A2 += x2 * w; A3 += x3 * w;
    }
    // reduce across the 8 edge slots (lane bits 3,4,5)
    float v[8] = {A0.x, A0.y, A1.x, A1.y, A2.x, A2.y, A3.x, A3.y};
    #pragma unroll
    for (int s = 8; s <= 32; s <<= 1) {
        L += __shfl_xor(L, s);
        #pragma unroll
        for (int k = 0; k < 8; ++k) v[k] += __shfl_xor(v[k], s);
    }
    float inv = 1.f / (L + SM_EPS);
    const float4 b0 = *reinterpret_cast<const float4*>(bias + fs);
    const float4 b1 = *reinterpret_cast<const float4*>(bias + fs + 4);
    float o[8];
    o[0] = v[0] * inv + b0.x; o[1] = v[1] * inv + b0.y;
    o[2] = v[2] * inv + b0.z; o[3] = v[3] * inv + b0.w;
    o[4] = v[4] * inv + b1.x; o[5] = v[5] * inv + b1.y;
    o[6] = v[6] * inv + b1.z; o[7] = v[7] * inv + b1.w;
    float psum = 0.f;
    #pragma unroll
    for (int k = 0; k < 8; ++k) psum += o[k];
    float mu = red8(psum) * 0.015625f;
    float d[8], vsum = 0.f;
    #pragma unroll
    for (int k = 0; k < 8; ++k) { d[k] = o[k] - mu; vsum += d[k] * d[k]; }
    float istd = rsqrtf(red8(vsum) * 0.015625f + LN_EPS);
    const float4 g0 = *reinterpret_cast<const float4*>(lng + fs);
    const float4 g1 = *reinterpret_cast<const float4*>(lng + fs + 4);
    const float4 bb0 = *reinterpret_cast<const float4*>(lnb + fs);
    const float4 bb1 = *reinterpret_cast<const float4*>(lnb + fs + 4);
    if (lane < 8) {
        float4 y0, y1;
        y0.x = d[0] * istd * g0.x + bb0.x;
        y0.y = d[1] * istd * g0.y + bb0.y;
        y0.z = d[2] * istd * g0.z + bb0.z;
        y0.w = d[3] * istd * g0.w + bb0.w;
        y1.x = d[4] * istd * g1.x + bb1.x;
        y1.y = d[5] * istd * g1.y + bb1.y;
        y1.z = d[6] * istd * g1.z + bb1.z;
        y1.w = d[7] * istd * g1.w + bb1.w;
        *reinterpret_cast<float4*>(out + (size_t)i * 64 + fs) = y0;
        *reinterpret_cast<float4*>(out + (size_t)i * 64 + fs + 4) = y1;
    }
}

extern "C" void kernel_launch(void* const* d_in, const int* in_sizes, int n_in,
                              void* d_out, int out_size, void* d_ws, size_t ws_size,
                              hipStream_t stream) {
    const float* x    = (const float*)d_in[0];
    const int*   ei   = (const int*)d_in[1];
    const float* W1l  = (const float*)d_in[2];
    const float* W1r  = (const float*)d_in[3];
    const float* att1 = (const float*)d_in[4];
    const float* b1   = (const float*)d_in[5];
    const float* ln1g = (const float*)d_in[6];
    const float* ln1b = (const float*)d_in[7];
    const float* W2l  = (const float*)d_in[8];
    const float* W2r  = (const float*)d_in[9];
    const float* att2 = (const float*)d_in[10];
    const float* b2   = (const float*)d_in[11];
    const float* ln2g = (const float*)d_in[12];
    const float* ln2b = (const float*)d_in[13];
    float* out = (float*)d_out;

    char* w = (char*)d_ws;
    size_t off = 0;
    auto alloc = [&](size_t bytes) -> void* {
        void* p = w + off;
        off += (bytes + 255) & ~(size_t)255;
        return p;
    };
    __hip_bfloat16* xl1  = (__hip_bfloat16*)alloc((size_t)NNODES * 256 * 2);
    __hip_bfloat16* xr1  = (__hip_bfloat16*)alloc((size_t)NNODES * 256 * 2);
    __hip_bfloat16* h1b  = (__hip_bfloat16*)alloc((size_t)NNODES * 64 * 2);
    __hip_bfloat16* xl2  = (__hip_bfloat16*)alloc((size_t)NNODES * 64 * 2);
    __hip_bfloat16* xr2  = (__hip_bfloat16*)alloc((size_t)NNODES * 64 * 2);
    __hip_bfloat16* w1lT = (__hip_bfloat16*)alloc(256 * 256 * 2);
    __hip_bfloat16* w1rT = (__hip_bfloat16*)alloc(256 * 256 * 2);
    __hip_bfloat16* w2lT = (__hip_bfloat16*)alloc(64 * 64 * 2);
    __hip_bfloat16* w2rT = (__hip_bfloat16*)alloc(64 * 64 * 2);
    int* part     = (int*)alloc((size_t)256 * NBLK * 4);       // per-(bucket,block)
    unsigned* pairs = (unsigned*)alloc((size_t)ETOT * 4);
    int* rowstart = (int*)alloc((size_t)(NNODES + 1) * 4);
    unsigned short* csr_src = (unsigned short*)alloc((size_t)(ETOT + 16) * 2);
    int* blocksum = (int*)alloc(1024);
    (void)ws_size; (void)in_sizes; (void)n_in; (void)out_size;

    k_cast_w<<<544, 256, 0, stream>>>(W1l, W1r, W2l, W2r,
                                      w1lT, w1rT, w2lT, w2rT, csr_src, rowstart);

    // ---- CSR build: bucket sort (196 buckets of 256 nodes), zero global atomics
    k_bhist<<<NBLK, 256, 0, stream>>>(ei, part);
    const int partN = 256 * NBLK;                       // 53248
    k_scan_blk<<<partN / 256, 256, 0, stream>>>(part, partN, part, blocksum);
    k_scan_top<<<1, 256, 0, stream>>>(blocksum, partN / 256);
    k_scan_add<<<partN / 256, 256, 0, stream>>>(part, blocksum, partN);
    k_bscatter<<<NBLK, 256, 0, stream>>>(ei, part, pairs);
    k_nfinal<<<NBUCK, 256, 0, stream>>>(pairs, part, rowstart, csr_src);

    // ---- dense pipeline
    const int gm = (NNODES + 63) / 64;                  // 782
    dim3 g1(gm, 2);
    k_gemm_x1<<<g1, 256, 0, stream>>>(x, w1lT, w1rT, xl1, xr1, NNODES);
    k_node1<<<NNODES, 64, 0, stream>>>(xl1, xr1, rowstart, csr_src,
                                       att1, b1, ln1g, ln1b, h1b);
    k_gemm_dual<<<gm, 256, 0, stream>>>(h1b, w2lT, w2rT, xl2, xr2, NNODES);
    k_node2<<<NNODES, 64, 0, stream>>>(xl2, xr2, rowstart, csr_src,
                                       att2, b2, ln2g, ln2b, out);
}